// Round 8
// baseline (489.642 us; speedup 1.0000x reference)
//
#include <hip/hip_runtime.h>
#include <hip/hip_bf16.h>
#include <stdint.h>

#define TOK   16384
#define DIM   256
#define HIDN  1024
#define OUTD  256
#define NEXP  8
#define NSH   3
#define NSLOT 11
#define TM    128
#define NCH   16      // hidden chunks of 64 cols

typedef short bf16x8  __attribute__((ext_vector_type(8)));
typedef float f32x4   __attribute__((ext_vector_type(4)));
typedef short short4v __attribute__((ext_vector_type(4)));

// ---- workspace layout (bytes) ----
constexpr size_t XB_OFF   = 0;                                        // T*D bf16
constexpr size_t W1P_OFF  = XB_OFF  + (size_t)TOK*DIM*2;
constexpr size_t W2P_OFF  = W1P_OFF + (size_t)NSLOT*DIM*HIDN*2;
constexpr size_t WTS_OFF  = W2P_OFF + (size_t)NSLOT*HIDN*OUTD*2;
constexpr size_t IDS_OFF  = WTS_OFF + (size_t)TOK*2*4;
constexpr size_t CNT_OFF  = IDS_OFF + (size_t)TOK*2*4;
constexpr size_t LTOK_OFF = CNT_OFF + 256;
constexpr size_t LW_OFF   = LTOK_OFF + (size_t)NEXP*TOK*4;
constexpr size_t WS_NEED  = LW_OFF + (size_t)NEXP*TOK*4;

__device__ __forceinline__ unsigned short f2bf(float f) {
    __hip_bfloat16 h = __float2bfloat16(f);
    return *reinterpret_cast<unsigned short*>(&h);
}

__device__ __forceinline__ f32x4 mfma16(bf16x8 a, bf16x8 b, f32x4 c) {
    return __builtin_amdgcn_mfma_f32_16x16x32_bf16(a, b, c, 0, 0, 0);
}

// async global->LDS: 16B/lane; global src per-lane, LDS dst uniform base.
__device__ __forceinline__ void gload_lds16(const void* g, void* l) {
    __builtin_amdgcn_global_load_lds(
        (const __attribute__((address_space(1))) unsigned int*)g,
        (__attribute__((address_space(3))) unsigned int*)l, 16, 0, 0);
}

// swizzle for 128x64 bf16 H tile (row stride 128B)
__device__ __forceinline__ int hswz(int row, int colb) {
    return ((row << 7) + colb) ^ ((row & 7) << 4);
}

// ---- fused: fp32->bf16 convert of X + fp32-exact gating (one X pass) ----
// One wave per token. Gate reduction order IDENTICAL to prior rounds
// (d = i*64+lane, shfl_xor tree) to keep top-k selection bit-stable.
__global__ __launch_bounds__(256) void k_prep(
    const float* __restrict__ x, const float* __restrict__ gw,
    const float* __restrict__ gb, short* __restrict__ xb,
    float* __restrict__ wts, int* __restrict__ ids) {
    int wid = threadIdx.x >> 6, lane = threadIdx.x & 63;
    int t = blockIdx.x * 4 + wid;
    const float* xr = x + (size_t)t * DIM;
    // convert: one float4 per lane
    {
        float4 v = reinterpret_cast<const float4*>(xr)[lane];
        short4v o;
        o[0] = (short)f2bf(v.x); o[1] = (short)f2bf(v.y);
        o[2] = (short)f2bf(v.z); o[3] = (short)f2bf(v.w);
        reinterpret_cast<short4v*>(xb + (size_t)t * DIM)[lane] = o;
    }
    // gate logits (same order as before, L1 re-hit on X row)
    float acc[NEXP] = {0.f,0.f,0.f,0.f,0.f,0.f,0.f,0.f};
    #pragma unroll
    for (int i = 0; i < DIM/64; ++i) {
        int d = i*64 + lane;
        float xv = xr[d];
        const float* g = gw + (size_t)d * NEXP;
        #pragma unroll
        for (int e = 0; e < NEXP; ++e) acc[e] = fmaf(xv, g[e], acc[e]);
    }
    #pragma unroll
    for (int off = 32; off; off >>= 1) {
        #pragma unroll
        for (int e = 0; e < NEXP; ++e) acc[e] += __shfl_xor(acc[e], off, 64);
    }
    if (lane == 0) {
        float l[NEXP];
        #pragma unroll
        for (int e = 0; e < NEXP; ++e) l[e] = acc[e] + gb[e];
        int e0 = 0; float v0 = l[0];
        #pragma unroll
        for (int e = 1; e < NEXP; ++e) if (l[e] > v0) { v0 = l[e]; e0 = e; }
        int e1 = -1; float v1 = -1e30f;
        #pragma unroll
        for (int e = 0; e < NEXP; ++e) if (e != e0 && l[e] > v1) { v1 = l[e]; e1 = e; }
        float r = expf(v1 - v0);
        float w0 = 0.5f / (1.f + r);
        float w1 = 0.5f * r / (1.f + r);
        ids[2*t]   = e0;  ids[2*t+1] = e1;
        wts[2*t]   = w0;  wts[2*t+1] = w1;
    }
}

// ---- fp32 weights -> bf16 packed B-frag order, via LDS transpose ----
__global__ __launch_bounds__(256) void k_convert_w(
    const float* __restrict__ sw1, const float* __restrict__ iw1,
    const float* __restrict__ sw2, const float* __restrict__ iw2,
    short* __restrict__ w1p, short* __restrict__ w2p) {
    __shared__ float tile[32][68];
    int bid = blockIdx.x, tid = threadIdx.x;
    const int W1B = NSLOT * 8 * 16;            // 1408
    bool isW1 = bid < W1B;
    int b = isW1 ? bid : bid - W1B;
    int NTG = isW1 ? 16 : 4;
    int KT  = isW1 ? 8 : 32;
    int NT  = isW1 ? 64 : 16;
    int Nd  = isW1 ? HIDN : OUTD;
    int ntg = b % NTG; b /= NTG;
    int kt  = b % KT;
    int slot = b / KT;
    const float* src;
    if (isW1) src = (slot < NSH) ? sw1 + (size_t)slot*DIM*HIDN  : iw1 + (size_t)(slot-NSH)*DIM*HIDN;
    else      src = (slot < NSH) ? sw2 + (size_t)slot*HIDN*OUTD : iw2 + (size_t)(slot-NSH)*HIDN*OUTD;
    {
        int tr = tid >> 3, tc = (tid & 7) * 8;
        const float* s = src + (size_t)(kt*32 + tr)*Nd + ntg*64 + tc;
        float4 v0 = *reinterpret_cast<const float4*>(s);
        float4 v1 = *reinterpret_cast<const float4*>(s + 4);
        *reinterpret_cast<float4*>(&tile[tr][tc])     = v0;
        *reinterpret_cast<float4*>(&tile[tr][tc + 4]) = v1;
    }
    __syncthreads();
    {
        int ntl = tid >> 6, lane = tid & 63;
        int n  = ntl*16 + (lane & 15);
        int k8 = (lane >> 4) * 8;
        bf16x8 o;
        #pragma unroll
        for (int j = 0; j < 8; ++j) o[j] = (short)f2bf(tile[k8 + j][n]);
        size_t gidx = (((size_t)slot*KT + kt)*NT + ntg*4 + ntl)*64 + lane;
        short* dst = isW1 ? w1p : w2p;
        reinterpret_cast<bf16x8*>(dst)[gidx] = o;
    }
}

// ---- route: LDS histogram -> 8 global atomics per block (was 32K global) ----
__global__ __launch_bounds__(256) void k_route(
    const int* __restrict__ ids, const float* __restrict__ wts,
    int* __restrict__ cnt, int* __restrict__ ltok, float* __restrict__ lw) {
    __shared__ int lcnt[NEXP];
    __shared__ int gbase[NEXP];
    int tid = threadIdx.x;
    if (tid < NEXP) lcnt[tid] = 0;
    __syncthreads();
    int t = blockIdx.x * 256 + tid;
    int e0 = ids[2*t], e1 = ids[2*t+1];
    int p0 = atomicAdd(&lcnt[e0], 1);
    int p1 = atomicAdd(&lcnt[e1], 1);
    __syncthreads();
    if (tid < NEXP) gbase[tid] = atomicAdd(&cnt[tid], lcnt[tid]);
    __syncthreads();
    size_t o0 = (size_t)e0*TOK + gbase[e0] + p0;
    size_t o1 = (size_t)e1*TOK + gbase[e1] + p1;
    ltok[o0] = t;  lw[o0] = wts[2*t];
    ltok[o1] = t;  lw[o1] = wts[2*t+1];
}

// ---- mega-kernel v5: block=(128-token tile, slot), 8 waves (4m x 2n) ----
// LDS 65KB -> 2 blocks/CU (m114 inter-block overlap covers stage drains).
// H (16KB) aliases the W1 chunk buffer (dead after phase 1). Single-buffered
// global_load_lds staging, plain __syncthreads (m97 pattern).
__global__ __launch_bounds__(512, 4) void k_moe(
    const short* __restrict__ xb, const short* __restrict__ w1p, const short* __restrict__ w2p,
    const float* __restrict__ sb1, const float* __restrict__ sb2,
    const float* __restrict__ ib1, const float* __restrict__ ib2,
    const float* __restrict__ obj, const int* __restrict__ cnt,
    const int* __restrict__ ltok, const float* __restrict__ lw,
    float* __restrict__ out)
{
    __shared__ __align__(16) char Wb1[32768];   // [kt 0..7][ntl 0..3] x 1KB; Hs aliases [0,16K)
    __shared__ __align__(16) char Wb2[32768];   // [kt2 0..1][nt 0..15] x 1KB
    __shared__ int   tokl[TM];
    __shared__ float twl[TM];
    char* Hs = Wb1;

    const int slot = blockIdx.y;
    const int m0   = blockIdx.x * TM;
    const bool sh  = slot < NSH;
    const int e    = slot - NSH;
    int count = TOK;
    if (!sh) { count = cnt[e]; if (m0 >= count) return; }

    const int tid  = threadIdx.x;
    const int w    = tid >> 6, lane = tid & 63;
    const int wm   = w >> 1,   wn   = w & 1;       // 4m x 2n waves
    const int lrow = lane & 15, g   = lane >> 4;

    if (tid < TM) {
        if (sh) {
            tokl[tid] = m0 + tid;
            twl[tid]  = 0.5f * obj[(size_t)(m0 + tid)*NSH + slot];
        } else {
            int p = m0 + tid;
            bool ok = p < count;
            tokl[tid] = ok ? ltok[(size_t)e*TOK + p] : 0;
            twl[tid]  = ok ? lw[(size_t)e*TOK + p] : 0.f;   // already 0.5-scaled
        }
    }
    __syncthreads();

    // ---- X rows of this wave -> registers (read once per block) ----
    int tA[2];
    #pragma unroll
    for (int m = 0; m < 2; ++m) tA[m] = tokl[wm*32 + m*16 + lrow];
    bf16x8 areg[2][8];
    #pragma unroll
    for (int m = 0; m < 2; ++m)
        #pragma unroll
        for (int kt = 0; kt < 8; ++kt)
            areg[m][kt] = *reinterpret_cast<const bf16x8*>(
                xb + (size_t)tA[m]*DIM + kt*32 + g*8);

    const char* w1base = (const char*)w1p;
    const char* w2base = (const char*)w2p;
    const float* b1v = sh ? (sb1 + slot*HIDN) : (ib1 + (size_t)e*HIDN);

    // stage chunk c (64KB): wave w does 4 W1 segs (kt=w) + 4 W2 segs
    auto stage = [&](int c) {
        #pragma unroll
        for (int i = 0; i < 4; ++i) {
            int s = w*4 + i;                       // kt = w, ntl = i
            gload_lds16(
                w1base + ((((size_t)slot*8 + w)*64 + c*4 + i) << 10) + lane*16,
                Wb1 + (s << 10));
        }
        {
            const char* s2 = w2base + ((((size_t)slot*32 + c*2)*16) << 10);
            #pragma unroll
            for (int i = 0; i < 4; ++i) {
                int s = w*4 + i;                   // kt2 = s>>4, nt = s&15
                gload_lds16(s2 + (s << 10) + lane*16, Wb2 + (s << 10));
            }
        }
    };

    stage(0);

    f32x4 acc2[2][8] = {};                         // out wave-tile 32 x 128
    for (int c = 0; c < NCH; ++c) {
        __syncthreads();                           // stage(c) drained (vmcnt0)

        // ---- phase 1: acc1 = X(regs) @ W1c, wave tile 32r x 32c ----
        f32x4 acc1[2][2] = {};
        #pragma unroll
        for (int kt = 0; kt < 8; ++kt) {
            bf16x8 b0 = *reinterpret_cast<const bf16x8*>(
                Wb1 + ((kt*4 + wn*2 + 0) << 10) + lane*16);
            bf16x8 b1 = *reinterpret_cast<const bf16x8*>(
                Wb1 + ((kt*4 + wn*2 + 1) << 10) + lane*16);
            #pragma unroll
            for (int m = 0; m < 2; ++m) {
                acc1[m][0] = mfma16(areg[m][kt], b0, acc1[m][0]);
                acc1[m][1] = mfma16(areg[m][kt], b1, acc1[m][1]);
            }
        }
        __syncthreads();                           // all W1c reads done (alias!)

        // H = relu(acc1 + b1)*tw -> swizzled LDS bf16 (into Wb1[0:16K))
        #pragma unroll
        for (int n = 0; n < 2; ++n) {
            int col = wn*32 + n*16 + lrow;         // chunk-local col
            float bias = b1v[c*64 + col];
            #pragma unroll
            for (int m = 0; m < 2; ++m)
                #pragma unroll
                for (int r = 0; r < 4; ++r) {
                    int row = wm*32 + m*16 + g*4 + r;
                    float v = fmaxf(acc1[m][n][r] + bias, 0.f) * twl[row];
                    *reinterpret_cast<unsigned short*>(Hs + hswz(row, col*2)) = f2bf(v);
                }
        }
        __syncthreads();                           // H visible

        // ---- phase 2: acc2 += H(128x64) @ W2c(64x256), wave tile 32x128 ----
        #pragma unroll
        for (int kt2 = 0; kt2 < 2; ++kt2) {
            bf16x8 a2[2];
            #pragma unroll
            for (int m = 0; m < 2; ++m)
                a2[m] = *reinterpret_cast<const bf16x8*>(
                    Hs + hswz(wm*32 + m*16 + lrow, kt2*64 + g*16));
            #pragma unroll
            for (int n = 0; n < 8; ++n) {
                bf16x8 b2 = *reinterpret_cast<const bf16x8*>(
                    Wb2 + ((kt2*16 + wn*8 + n) << 10) + lane*16);
                #pragma unroll
                for (int m = 0; m < 2; ++m)
                    acc2[m][n] = mfma16(a2[m], b2, acc2[m][n]);
            }
        }
        if (c + 1 < NCH) {
            __syncthreads();                       // phase-2 reads done
            stage(c + 1);                          // overwrite Wb1/Wb2
        }
    }

    // ---- epilogue: one atomic pass (+ tw*b2) ----
    {
        const float* b2 = sh ? (sb2 + slot*OUTD) : (ib2 + (size_t)e*OUTD);
        #pragma unroll
        for (int m = 0; m < 2; ++m)
            #pragma unroll
            for (int n = 0; n < 8; ++n) {
                int col = wn*128 + n*16 + lrow;
                #pragma unroll
                for (int r = 0; r < 4; ++r) {
                    int row = wm*32 + m*16 + g*4 + r;
                    if (sh || (m0 + row < count)) {
                        int t = tokl[row];
                        float v = acc2[m][n][r] + twl[row] * b2[col];
                        atomicAdd(&out[(size_t)t*OUTD + col], v);
                    }
                }
            }
    }
}

extern "C" void kernel_launch(void* const* d_in, const int* in_sizes, int n_in,
                              void* d_out, int out_size, void* d_ws, size_t ws_size,
                              hipStream_t stream) {
    const float* x   = (const float*)d_in[0];
    const float* obj = (const float*)d_in[1];
    const float* gw  = (const float*)d_in[2];
    const float* gb  = (const float*)d_in[3];
    const float* sw1 = (const float*)d_in[4];
    const float* sb1 = (const float*)d_in[5];
    const float* sw2 = (const float*)d_in[6];
    const float* sb2 = (const float*)d_in[7];
    const float* iw1 = (const float*)d_in[8];
    const float* ib1 = (const float*)d_in[9];
    const float* iw2 = (const float*)d_in[10];
    const float* ib2 = (const float*)d_in[11];
    float* out = (float*)d_out;
    char* ws = (char*)d_ws;
    if (ws_size < WS_NEED) return;

    short* xb   = (short*)(ws + XB_OFF);
    short* w1p  = (short*)(ws + W1P_OFF);
    short* w2p  = (short*)(ws + W2P_OFF);
    float* wts  = (float*)(ws + WTS_OFF);
    int*   ids  = (int*)  (ws + IDS_OFF);
    int*   cnt  = (int*)  (ws + CNT_OFF);
    int*   ltok = (int*)  (ws + LTOK_OFF);
    float* lwt  = (float*)(ws + LW_OFF);

    hipMemsetAsync(ws + CNT_OFF, 0, 256, stream);
    hipMemsetAsync(out, 0, (size_t)out_size * 4, stream);
    k_prep<<<TOK/4, 256, 0, stream>>>(x, gw, gb, xb, wts, ids);
    k_convert_w<<<NSLOT*8*16 + NSLOT*32*4, 256, 0, stream>>>(sw1, iw1, sw2, iw2, w1p, w2p);
    k_route<<<TOK/256, 256, 0, stream>>>(ids, wts, cnt, ltok, lwt);
    k_moe<<<dim3(TOK/TM, NSLOT), 512, 0, stream>>>(
        xb, w1p, w2p, sb1, sb2, ib1, ib2, obj, cnt, ltok, lwt, out);
}

// Round 9
// 272.128 us; speedup vs baseline: 1.7993x; 1.7993x over previous
//
#include <hip/hip_runtime.h>
#include <hip/hip_bf16.h>
#include <stdint.h>

#define TOK   16384
#define DIM   256
#define HIDN  1024
#define OUTD  256
#define NEXP  8
#define NSH   3
#define NSLOT 11
#define TM    128
#define NCH   16      // hidden chunks of 64 cols

typedef short bf16x8  __attribute__((ext_vector_type(8)));
typedef float f32x4   __attribute__((ext_vector_type(4)));
typedef short short4v __attribute__((ext_vector_type(4)));

// ---- workspace layout (bytes) ----
constexpr size_t XB_OFF   = 0;                                        // T*D bf16
constexpr size_t W1P_OFF  = XB_OFF  + (size_t)TOK*DIM*2;
constexpr size_t W2P_OFF  = W1P_OFF + (size_t)NSLOT*DIM*HIDN*2;
constexpr size_t WTS_OFF  = W2P_OFF + (size_t)NSLOT*HIDN*OUTD*2;
constexpr size_t IDS_OFF  = WTS_OFF + (size_t)TOK*2*4;
constexpr size_t CNT_OFF  = IDS_OFF + (size_t)TOK*2*4;
constexpr size_t LTOK_OFF = CNT_OFF + 256;
constexpr size_t LW_OFF   = LTOK_OFF + (size_t)NEXP*TOK*4;
constexpr size_t WS_NEED  = LW_OFF + (size_t)NEXP*TOK*4;

__device__ __forceinline__ unsigned short f2bf(float f) {
    __hip_bfloat16 h = __float2bfloat16(f);
    return *reinterpret_cast<unsigned short*>(&h);
}

__device__ __forceinline__ f32x4 mfma16(bf16x8 a, bf16x8 b, f32x4 c) {
    return __builtin_amdgcn_mfma_f32_16x16x32_bf16(a, b, c, 0, 0, 0);
}

// async global->LDS: 16B/lane; global src per-lane, LDS dst uniform base.
__device__ __forceinline__ void gload_lds16(const void* g, void* l) {
    __builtin_amdgcn_global_load_lds(
        (const __attribute__((address_space(1))) unsigned int*)g,
        (__attribute__((address_space(3))) unsigned int*)l, 16, 0, 0);
}

// swizzle for 128x64 bf16 H tile (row stride 128B)
__device__ __forceinline__ int hswz(int row, int colb) {
    return ((row << 7) + colb) ^ ((row & 7) << 4);
}

// ---- fused: fp32->bf16 convert of X + fp32-exact gating (one X pass) ----
__global__ __launch_bounds__(256) void k_prep(
    const float* __restrict__ x, const float* __restrict__ gw,
    const float* __restrict__ gb, short* __restrict__ xb,
    float* __restrict__ wts, int* __restrict__ ids) {
    int wid = threadIdx.x >> 6, lane = threadIdx.x & 63;
    int t = blockIdx.x * 4 + wid;
    const float* xr = x + (size_t)t * DIM;
    {
        float4 v = reinterpret_cast<const float4*>(xr)[lane];
        short4v o;
        o[0] = (short)f2bf(v.x); o[1] = (short)f2bf(v.y);
        o[2] = (short)f2bf(v.z); o[3] = (short)f2bf(v.w);
        reinterpret_cast<short4v*>(xb + (size_t)t * DIM)[lane] = o;
    }
    float acc[NEXP] = {0.f,0.f,0.f,0.f,0.f,0.f,0.f,0.f};
    #pragma unroll
    for (int i = 0; i < DIM/64; ++i) {
        int d = i*64 + lane;
        float xv = xr[d];
        const float* g = gw + (size_t)d * NEXP;
        #pragma unroll
        for (int e = 0; e < NEXP; ++e) acc[e] = fmaf(xv, g[e], acc[e]);
    }
    #pragma unroll
    for (int off = 32; off; off >>= 1) {
        #pragma unroll
        for (int e = 0; e < NEXP; ++e) acc[e] += __shfl_xor(acc[e], off, 64);
    }
    if (lane == 0) {
        float l[NEXP];
        #pragma unroll
        for (int e = 0; e < NEXP; ++e) l[e] = acc[e] + gb[e];
        int e0 = 0; float v0 = l[0];
        #pragma unroll
        for (int e = 1; e < NEXP; ++e) if (l[e] > v0) { v0 = l[e]; e0 = e; }
        int e1 = -1; float v1 = -1e30f;
        #pragma unroll
        for (int e = 0; e < NEXP; ++e) if (e != e0 && l[e] > v1) { v1 = l[e]; e1 = e; }
        float r = expf(v1 - v0);
        float w0 = 0.5f / (1.f + r);
        float w1 = 0.5f * r / (1.f + r);
        ids[2*t]   = e0;  ids[2*t+1] = e1;
        wts[2*t]   = w0;  wts[2*t+1] = w1;
    }
}

// ---- fp32 weights -> bf16 packed B-frag order, via LDS transpose ----
__global__ __launch_bounds__(256) void k_convert_w(
    const float* __restrict__ sw1, const float* __restrict__ iw1,
    const float* __restrict__ sw2, const float* __restrict__ iw2,
    short* __restrict__ w1p, short* __restrict__ w2p) {
    __shared__ float tile[32][68];
    int bid = blockIdx.x, tid = threadIdx.x;
    const int W1B = NSLOT * 8 * 16;            // 1408
    bool isW1 = bid < W1B;
    int b = isW1 ? bid : bid - W1B;
    int NTG = isW1 ? 16 : 4;
    int KT  = isW1 ? 8 : 32;
    int NT  = isW1 ? 64 : 16;
    int Nd  = isW1 ? HIDN : OUTD;
    int ntg = b % NTG; b /= NTG;
    int kt  = b % KT;
    int slot = b / KT;
    const float* src;
    if (isW1) src = (slot < NSH) ? sw1 + (size_t)slot*DIM*HIDN  : iw1 + (size_t)(slot-NSH)*DIM*HIDN;
    else      src = (slot < NSH) ? sw2 + (size_t)slot*HIDN*OUTD : iw2 + (size_t)(slot-NSH)*HIDN*OUTD;
    {
        int tr = tid >> 3, tc = (tid & 7) * 8;
        const float* s = src + (size_t)(kt*32 + tr)*Nd + ntg*64 + tc;
        float4 v0 = *reinterpret_cast<const float4*>(s);
        float4 v1 = *reinterpret_cast<const float4*>(s + 4);
        *reinterpret_cast<float4*>(&tile[tr][tc])     = v0;
        *reinterpret_cast<float4*>(&tile[tr][tc + 4]) = v1;
    }
    __syncthreads();
    {
        int ntl = tid >> 6, lane = tid & 63;
        int n  = ntl*16 + (lane & 15);
        int k8 = (lane >> 4) * 8;
        bf16x8 o;
        #pragma unroll
        for (int j = 0; j < 8; ++j) o[j] = (short)f2bf(tile[k8 + j][n]);
        size_t gidx = (((size_t)slot*KT + kt)*NT + ntg*4 + ntl)*64 + lane;
        short* dst = isW1 ? w1p : w2p;
        reinterpret_cast<bf16x8*>(dst)[gidx] = o;
    }
}

// ---- route: LDS histogram -> 8 global atomics per block ----
__global__ __launch_bounds__(256) void k_route(
    const int* __restrict__ ids, const float* __restrict__ wts,
    int* __restrict__ cnt, int* __restrict__ ltok, float* __restrict__ lw) {
    __shared__ int lcnt[NEXP];
    __shared__ int gbase[NEXP];
    int tid = threadIdx.x;
    if (tid < NEXP) lcnt[tid] = 0;
    __syncthreads();
    int t = blockIdx.x * 256 + tid;
    int e0 = ids[2*t], e1 = ids[2*t+1];
    int p0 = atomicAdd(&lcnt[e0], 1);
    int p1 = atomicAdd(&lcnt[e1], 1);
    __syncthreads();
    if (tid < NEXP) gbase[tid] = atomicAdd(&cnt[tid], lcnt[tid]);
    __syncthreads();
    size_t o0 = (size_t)e0*TOK + gbase[e0] + p0;
    size_t o1 = (size_t)e1*TOK + gbase[e1] + p1;
    ltok[o0] = t;  lw[o0] = wts[2*t];
    ltok[o1] = t;  lw[o1] = wts[2*t+1];
}

// ---- mega-kernel v5b: identical to v5 but __launch_bounds__(512, 2).
// Empirical: 2nd arg acts as min BLOCKS/CU on this toolchain; (512,4) forced
// a 64-VGPR cap and massive spills (r8: FETCH 596MB). (512,2) -> 128-VGPR cap,
// 2 blocks/CU via the 65KB LDS; sibling block covers stage drains (m114).
__global__ __launch_bounds__(512, 2) void k_moe(
    const short* __restrict__ xb, const short* __restrict__ w1p, const short* __restrict__ w2p,
    const float* __restrict__ sb1, const float* __restrict__ sb2,
    const float* __restrict__ ib1, const float* __restrict__ ib2,
    const float* __restrict__ obj, const int* __restrict__ cnt,
    const int* __restrict__ ltok, const float* __restrict__ lw,
    float* __restrict__ out)
{
    __shared__ __align__(16) char Wb1[32768];   // [kt 0..7][ntl 0..3] x 1KB; Hs aliases [0,16K)
    __shared__ __align__(16) char Wb2[32768];   // [kt2 0..1][nt 0..15] x 1KB
    __shared__ int   tokl[TM];
    __shared__ float twl[TM];
    char* Hs = Wb1;

    const int slot = blockIdx.y;
    const int m0   = blockIdx.x * TM;
    const bool sh  = slot < NSH;
    const int e    = slot - NSH;
    int count = TOK;
    if (!sh) { count = cnt[e]; if (m0 >= count) return; }

    const int tid  = threadIdx.x;
    const int w    = tid >> 6, lane = tid & 63;
    const int wm   = w >> 1,   wn   = w & 1;       // 4m x 2n waves
    const int lrow = lane & 15, g   = lane >> 4;

    if (tid < TM) {
        if (sh) {
            tokl[tid] = m0 + tid;
            twl[tid]  = 0.5f * obj[(size_t)(m0 + tid)*NSH + slot];
        } else {
            int p = m0 + tid;
            bool ok = p < count;
            tokl[tid] = ok ? ltok[(size_t)e*TOK + p] : 0;
            twl[tid]  = ok ? lw[(size_t)e*TOK + p] : 0.f;   // already 0.5-scaled
        }
    }
    __syncthreads();

    // ---- X rows of this wave -> registers (read once per block) ----
    int tA[2];
    #pragma unroll
    for (int m = 0; m < 2; ++m) tA[m] = tokl[wm*32 + m*16 + lrow];
    bf16x8 areg[2][8];
    #pragma unroll
    for (int m = 0; m < 2; ++m)
        #pragma unroll
        for (int kt = 0; kt < 8; ++kt)
            areg[m][kt] = *reinterpret_cast<const bf16x8*>(
                xb + (size_t)tA[m]*DIM + kt*32 + g*8);

    const char* w1base = (const char*)w1p;
    const char* w2base = (const char*)w2p;
    const float* b1v = sh ? (sb1 + slot*HIDN) : (ib1 + (size_t)e*HIDN);

    // stage chunk c (64KB): wave w does 4 W1 segs (kt=w) + 4 W2 segs
    auto stage = [&](int c) {
        #pragma unroll
        for (int i = 0; i < 4; ++i) {
            int s = w*4 + i;                       // kt = w, ntl = i
            gload_lds16(
                w1base + ((((size_t)slot*8 + w)*64 + c*4 + i) << 10) + lane*16,
                Wb1 + (s << 10));
        }
        {
            const char* s2 = w2base + ((((size_t)slot*32 + c*2)*16) << 10);
            #pragma unroll
            for (int i = 0; i < 4; ++i) {
                int s = w*4 + i;                   // kt2 = s>>4, nt = s&15
                gload_lds16(s2 + (s << 10) + lane*16, Wb2 + (s << 10));
            }
        }
    };

    stage(0);

    f32x4 acc2[2][8] = {};                         // out wave-tile 32 x 128
    for (int c = 0; c < NCH; ++c) {
        __syncthreads();                           // stage(c) drained (vmcnt0)

        // ---- phase 1: acc1 = X(regs) @ W1c, wave tile 32r x 32c ----
        f32x4 acc1[2][2] = {};
        #pragma unroll
        for (int kt = 0; kt < 8; ++kt) {
            bf16x8 b0 = *reinterpret_cast<const bf16x8*>(
                Wb1 + ((kt*4 + wn*2 + 0) << 10) + lane*16);
            bf16x8 b1 = *reinterpret_cast<const bf16x8*>(
                Wb1 + ((kt*4 + wn*2 + 1) << 10) + lane*16);
            #pragma unroll
            for (int m = 0; m < 2; ++m) {
                acc1[m][0] = mfma16(areg[m][kt], b0, acc1[m][0]);
                acc1[m][1] = mfma16(areg[m][kt], b1, acc1[m][1]);
            }
        }
        __syncthreads();                           // all W1c reads done (alias!)

        // H = relu(acc1 + b1)*tw -> swizzled LDS bf16 (into Wb1[0:16K))
        #pragma unroll
        for (int n = 0; n < 2; ++n) {
            int col = wn*32 + n*16 + lrow;         // chunk-local col
            float bias = b1v[c*64 + col];
            #pragma unroll
            for (int m = 0; m < 2; ++m)
                #pragma unroll
                for (int r = 0; r < 4; ++r) {
                    int row = wm*32 + m*16 + g*4 + r;
                    float v = fmaxf(acc1[m][n][r] + bias, 0.f) * twl[row];
                    *reinterpret_cast<unsigned short*>(Hs + hswz(row, col*2)) = f2bf(v);
                }
        }
        __syncthreads();                           // H visible

        // ---- phase 2: acc2 += H(128x64) @ W2c(64x256), wave tile 32x128 ----
        #pragma unroll
        for (int kt2 = 0; kt2 < 2; ++kt2) {
            bf16x8 a2[2];
            #pragma unroll
            for (int m = 0; m < 2; ++m)
                a2[m] = *reinterpret_cast<const bf16x8*>(
                    Hs + hswz(wm*32 + m*16 + lrow, kt2*64 + g*16));
            #pragma unroll
            for (int n = 0; n < 8; ++n) {
                bf16x8 b2 = *reinterpret_cast<const bf16x8*>(
                    Wb2 + ((kt2*16 + wn*8 + n) << 10) + lane*16);
                #pragma unroll
                for (int m = 0; m < 2; ++m)
                    acc2[m][n] = mfma16(a2[m], b2, acc2[m][n]);
            }
        }
        if (c + 1 < NCH) {
            __syncthreads();                       // phase-2 reads done
            stage(c + 1);                          // overwrite Wb1/Wb2
        }
    }

    // ---- epilogue: one atomic pass (+ tw*b2) ----
    {
        const float* b2 = sh ? (sb2 + slot*OUTD) : (ib2 + (size_t)e*OUTD);
        #pragma unroll
        for (int m = 0; m < 2; ++m)
            #pragma unroll
            for (int n = 0; n < 8; ++n) {
                int col = wn*128 + n*16 + lrow;
                #pragma unroll
                for (int r = 0; r < 4; ++r) {
                    int row = wm*32 + m*16 + g*4 + r;
                    if (sh || (m0 + row < count)) {
                        int t = tokl[row];
                        float v = acc2[m][n][r] + twl[row] * b2[col];
                        atomicAdd(&out[(size_t)t*OUTD + col], v);
                    }
                }
            }
    }
}

extern "C" void kernel_launch(void* const* d_in, const int* in_sizes, int n_in,
                              void* d_out, int out_size, void* d_ws, size_t ws_size,
                              hipStream_t stream) {
    const float* x   = (const float*)d_in[0];
    const float* obj = (const float*)d_in[1];
    const float* gw  = (const float*)d_in[2];
    const float* gb  = (const float*)d_in[3];
    const float* sw1 = (const float*)d_in[4];
    const float* sb1 = (const float*)d_in[5];
    const float* sw2 = (const float*)d_in[6];
    const float* sb2 = (const float*)d_in[7];
    const float* iw1 = (const float*)d_in[8];
    const float* ib1 = (const float*)d_in[9];
    const float* iw2 = (const float*)d_in[10];
    const float* ib2 = (const float*)d_in[11];
    float* out = (float*)d_out;
    char* ws = (char*)d_ws;
    if (ws_size < WS_NEED) return;

    short* xb   = (short*)(ws + XB_OFF);
    short* w1p  = (short*)(ws + W1P_OFF);
    short* w2p  = (short*)(ws + W2P_OFF);
    float* wts  = (float*)(ws + WTS_OFF);
    int*   ids  = (int*)  (ws + IDS_OFF);
    int*   cnt  = (int*)  (ws + CNT_OFF);
    int*   ltok = (int*)  (ws + LTOK_OFF);
    float* lwt  = (float*)(ws + LW_OFF);

    hipMemsetAsync(ws + CNT_OFF, 0, 256, stream);
    hipMemsetAsync(out, 0, (size_t)out_size * 4, stream);
    k_prep<<<TOK/4, 256, 0, stream>>>(x, gw, gb, xb, wts, ids);
    k_convert_w<<<NSLOT*8*16 + NSLOT*32*4, 256, 0, stream>>>(sw1, iw1, sw2, iw2, w1p, w2p);
    k_route<<<TOK/256, 256, 0, stream>>>(ids, wts, cnt, ltok, lwt);
    k_moe<<<dim3(TOK/TM, NSLOT), 512, 0, stream>>>(
        xb, w1p, w2p, sb1, sb2, ib1, ib2, obj, cnt, ltok, lwt, out);
}